// Round 5
// baseline (1496.176 us; speedup 1.0000x reference)
//
#include <hip/hip_runtime.h>
#include <hip/hip_bf16.h>

#define NTOK 49
#define DIMC 256
#define WPB  8   // windows per block (persistent-ish, double-buffered)

typedef __attribute__((ext_vector_type(8))) short bf16x8;
typedef __attribute__((ext_vector_type(4))) float f32x4;

static __device__ __forceinline__ unsigned pk2(float a, float b) {
    union { __hip_bfloat16 h; unsigned short u; } ua, ub;
    ua.h = __float2bfloat16(a);
    ub.h = __float2bfloat16(b);
    return (unsigned)ua.u | ((unsigned)ub.u << 16);
}

static __device__ __forceinline__ bf16x8 mkfrag(unsigned w0, unsigned w1, unsigned w2, unsigned w3) {
    union { bf16x8 v; unsigned u[4]; } t;
    t.u[0] = w0; t.u[1] = w1; t.u[2] = w2; t.u[3] = w3;
    return t.v;
}

// pull both candidate halves from src lane, select by target's g>>1
static __device__ __forceinline__ unsigned sel2(unsigned lo, unsigned hi, int src, int ghi) {
    unsigned a = __shfl(lo, src);
    unsigned b = __shfl(hi, src);
    return ghi ? b : a;
}

__global__ void convert_weights(const float* __restrict__ wq, const float* __restrict__ wp,
                                unsigned short* __restrict__ wqb, unsigned short* __restrict__ wpb) {
    int i = blockIdx.x * 256 + threadIdx.x;
    if (i < 768 * 256) {
        union { __hip_bfloat16 h; unsigned short u; } t;
        t.h = __float2bfloat16(wq[i]);
        wqb[i] = t.u;
    }
    if (i < 256 * 256) {
        union { __hip_bfloat16 h; unsigned short u; } t;
        t.h = __float2bfloat16(wp[i]);
        wpb[i] = t.u;
    }
}

// 8 waves = 512 threads; wave h owns head h. Each block processes WPB windows
// with double-buffered x in LDS; next window's x prefetched into registers
// during proj (T14), written to the other buffer at window end.
// LDS (96KB, 1 block/CU):
//   xb[0] [0,32K), xb[1] [32K,64K) : x bf16 [64 t][512B rows], XOR swz ((t&7)<<4)
//   aob   [64K,96K)                : attn_out [64 t][256 d] bf16, same swizzle
// Mask is read directly from global (L2-served) in the softmax.
__launch_bounds__(512, 2)
__global__ void win_attn_fused(const float* __restrict__ x, const float* __restrict__ mask,
                               const unsigned short* __restrict__ wqkv, const float* __restrict__ bqkv,
                               const unsigned short* __restrict__ wproj, const float* __restrict__ bproj,
                               float* __restrict__ out) {
    __shared__ __align__(16) char lds[98304];
    char* const aob = lds + 65536;

    const int tid = threadIdx.x;
    const int lane = tid & 63;
    const int wid = tid >> 6;
    const int c = lane & 15;   // fragment row/col selector
    const int g = lane >> 4;   // 4-lane-group index 0..3
    const int h = wid;
    const int srcA = c + 16 * ((2 * g) & 3);
    const int srcB = c + 16 * ((2 * g + 1) & 3);
    const int ghi = g >> 1;
    const float scale = 0.17677669529663687f;  // 32^-0.5
    const f32x4 fzero = {0.f, 0.f, 0.f, 0.f};

    const int b0 = blockIdx.x * WPB;

    // ---------- prologue: stage window b0 x into buf 0 ----------
    {
        const float* xw = x + (size_t)b0 * (NTOK * DIMC);
        #pragma unroll
        for (int it = 0; it < 8; ++it) {
            int idx = it * 512 + tid;
            int t = idx >> 6;
            int d0 = (idx & 63) * 4;
            float4 v = make_float4(0.f, 0.f, 0.f, 0.f);
            if (t < NTOK) v = *(const float4*)(xw + t * DIMC + d0);
            *(uint2*)(lds + t * 512 + ((d0 * 2) ^ ((t & 7) << 4))) =
                make_uint2(pk2(v.x, v.y), pk2(v.z, v.w));
        }
    }
    __syncthreads();

    #pragma unroll 1
    for (int w = 0; w < WPB; ++w) {
        const int b = b0 + w;
        char* const xb = lds + (w & 1) * 32768;
        char* const xn = lds + ((w & 1) ^ 1) * 32768;

        #define XFR(base_, t_, kk_) \
            (*(const bf16x8*)((base_) + (t_) * 512 + ((2 * ((kk_) + 8 * g)) ^ (((t_) & 7) << 4))))

        // ---------- K & Q GEMMs merged (shared x fragments) ----------
        bf16x8 ka[4], qf[4];
        {
            f32x4 aK[2][4], aQ[2][4];
            #pragma unroll
            for (int md = 0; md < 2; ++md)
                #pragma unroll
                for (int j2 = 0; j2 < 4; ++j2) { aK[md][j2] = fzero; aQ[md][j2] = fzero; }
            #pragma unroll
            for (int ks = 0; ks < 8; ++ks) {
                int kk = ks * 32;
                bf16x8 bx[4];
                #pragma unroll
                for (int j2 = 0; j2 < 4; ++j2) { int t = j2 * 16 + c; bx[j2] = XFR(xb, t, kk); }
                #pragma unroll
                for (int md = 0; md < 2; ++md) {
                    bf16x8 wK = *(const bf16x8*)(wqkv + (256 + h * 32 + md * 16 + c) * 256 + kk + 8 * g);
                    bf16x8 wQ = *(const bf16x8*)(wqkv + (h * 32 + md * 16 + c) * 256 + kk + 8 * g);
                    #pragma unroll
                    for (int j2 = 0; j2 < 4; ++j2) {
                        aK[md][j2] = __builtin_amdgcn_mfma_f32_16x16x32_bf16(wK, bx[j2], aK[md][j2], 0, 0, 0);
                        aQ[md][j2] = __builtin_amdgcn_mfma_f32_16x16x32_bf16(wQ, bx[j2], aQ[md][j2], 0, 0, 0);
                    }
                }
            }
            unsigned kpp[2][4][2], qpp[2][4][2];
            #pragma unroll
            for (int md = 0; md < 2; ++md) {
                const float* bk = bqkv + 256 + h * 32 + md * 16 + 4 * g;
                float k0 = bk[0], k1 = bk[1], k2 = bk[2], k3 = bk[3];
                const float* bq = bqkv + h * 32 + md * 16 + 4 * g;
                float q0 = bq[0], q1 = bq[1], q2 = bq[2], q3 = bq[3];
                #pragma unroll
                for (int j2 = 0; j2 < 4; ++j2) {
                    kpp[md][j2][0] = pk2(aK[md][j2][0] + k0, aK[md][j2][1] + k1);
                    kpp[md][j2][1] = pk2(aK[md][j2][2] + k2, aK[md][j2][3] + k3);
                    qpp[md][j2][0] = pk2((aQ[md][j2][0] + q0) * scale, (aQ[md][j2][1] + q1) * scale);
                    qpp[md][j2][1] = pk2((aQ[md][j2][2] + q2) * scale, (aQ[md][j2][3] + q3) * scale);
                }
            }
            #pragma unroll
            for (int it = 0; it < 4; ++it) {
                ka[it] = mkfrag(sel2(kpp[0][it][0], kpp[1][it][0], srcA, ghi),
                                sel2(kpp[0][it][1], kpp[1][it][1], srcA, ghi),
                                sel2(kpp[0][it][0], kpp[1][it][0], srcB, ghi),
                                sel2(kpp[0][it][1], kpp[1][it][1], srcB, ghi));
                qf[it] = mkfrag(sel2(qpp[0][it][0], qpp[1][it][0], srcA, ghi),
                                sel2(qpp[0][it][1], qpp[1][it][1], srcA, ghi),
                                sel2(qpp[0][it][0], qpp[1][it][0], srcB, ghi),
                                sel2(qpp[0][it][1], qpp[1][it][1], srcB, ghi));
            }
        }

        // ---------- V = x · Wv -> PV A-frags vf[kh][dt] ----------
        bf16x8 vf[2][2];
        {
            f32x4 acc[4][2];
            #pragma unroll
            for (int mt = 0; mt < 4; ++mt)
                #pragma unroll
                for (int j2 = 0; j2 < 2; ++j2) acc[mt][j2] = fzero;
            #pragma unroll
            for (int ks = 0; ks < 8; ++ks) {
                int kk = ks * 32;
                bf16x8 ax[4];
                #pragma unroll
                for (int mt = 0; mt < 4; ++mt) { int t = mt * 16 + c; ax[mt] = XFR(xb, t, kk); }
                #pragma unroll
                for (int j2 = 0; j2 < 2; ++j2) {
                    bf16x8 wb = *(const bf16x8*)(wqkv + (512 + h * 32 + j2 * 16 + c) * 256 + kk + 8 * g);
                    #pragma unroll
                    for (int mt = 0; mt < 4; ++mt)
                        acc[mt][j2] = __builtin_amdgcn_mfma_f32_16x16x32_bf16(ax[mt], wb, acc[mt][j2], 0, 0, 0);
                }
            }
            float bv0 = bqkv[512 + h * 32 + c];
            float bv1 = bqkv[512 + h * 32 + 16 + c];
            unsigned vpp[4][2][2];
            #pragma unroll
            for (int mt = 0; mt < 4; ++mt) {
                vpp[mt][0][0] = pk2(acc[mt][0][0] + bv0, acc[mt][0][1] + bv0);
                vpp[mt][0][1] = pk2(acc[mt][0][2] + bv0, acc[mt][0][3] + bv0);
                vpp[mt][1][0] = pk2(acc[mt][1][0] + bv1, acc[mt][1][1] + bv1);
                vpp[mt][1][1] = pk2(acc[mt][1][2] + bv1, acc[mt][1][3] + bv1);
            }
            #pragma unroll
            for (int kh = 0; kh < 2; ++kh)
                #pragma unroll
                for (int dt = 0; dt < 2; ++dt)
                    vf[kh][dt] = mkfrag(sel2(vpp[2 * kh][dt][0], vpp[2 * kh + 1][dt][0], srcA, ghi),
                                        sel2(vpp[2 * kh][dt][1], vpp[2 * kh + 1][dt][1], srcA, ghi),
                                        sel2(vpp[2 * kh][dt][0], vpp[2 * kh + 1][dt][0], srcB, ghi),
                                        sel2(vpp[2 * kh][dt][1], vpp[2 * kh + 1][dt][1], srcB, ghi));
        }

        // ---------- per query-tile: S^T = K·Q^T + mask (direct global), softmax, PV ----------
        f32x4 oacc[2][4];
        #pragma unroll
        for (int dt = 0; dt < 2; ++dt)
            #pragma unroll
            for (int jt = 0; jt < 4; ++jt) oacc[dt][jt] = fzero;

        const float* mw = mask + (size_t)b * (NTOK * NTOK);
        #pragma unroll
        for (int jt = 0; jt < 4; ++jt) {
            int q = jt * 16 + c;
            int qc = (q < NTOK) ? q : (NTOK - 1);   // clamp: q>=49 rows discarded later
            const float* mrow = mw + qc * NTOK;
            f32x4 mv0 = *(const f32x4*)(mrow + 0 + g * 4);
            f32x4 mv1 = *(const f32x4*)(mrow + 16 + g * 4);
            f32x4 mv2 = *(const f32x4*)(mrow + 32 + g * 4);
            float m48 = mrow[48];                    // only key=48 valid in tile 3
            float p[4][4];
            {
                f32x4 s = __builtin_amdgcn_mfma_f32_16x16x32_bf16(ka[0], qf[jt], fzero, 0, 0, 0);
                #pragma unroll
                for (int r = 0; r < 4; ++r) p[0][r] = s[r] + mv0[r];
            }
            {
                f32x4 s = __builtin_amdgcn_mfma_f32_16x16x32_bf16(ka[1], qf[jt], fzero, 0, 0, 0);
                #pragma unroll
                for (int r = 0; r < 4; ++r) p[1][r] = s[r] + mv1[r];
            }
            {
                f32x4 s = __builtin_amdgcn_mfma_f32_16x16x32_bf16(ka[2], qf[jt], fzero, 0, 0, 0);
                #pragma unroll
                for (int r = 0; r < 4; ++r) p[2][r] = s[r] + mv2[r];
            }
            {
                f32x4 s = __builtin_amdgcn_mfma_f32_16x16x32_bf16(ka[3], qf[jt], fzero, 0, 0, 0);
                #pragma unroll
                for (int r = 0; r < 4; ++r)
                    p[3][r] = (g == 0 && r == 0) ? (s[0] + m48) : -1e30f;
            }
            // softmax over keys; lanes {c, c+16, c+32, c+48} share a query column
            float m = -1e30f;
            #pragma unroll
            for (int it = 0; it < 4; ++it)
                #pragma unroll
                for (int r = 0; r < 4; ++r) m = fmaxf(m, p[it][r]);
            m = fmaxf(m, __shfl_xor(m, 16));
            m = fmaxf(m, __shfl_xor(m, 32));
            float ssum = 0.f;
            #pragma unroll
            for (int it = 0; it < 4; ++it)
                #pragma unroll
                for (int r = 0; r < 4; ++r) {
                    float e = __expf(p[it][r] - m);
                    p[it][r] = e;
                    ssum += e;
                }
            ssum += __shfl_xor(ssum, 16);
            ssum += __shfl_xor(ssum, 32);
            float inv = 1.0f / ssum;
            unsigned pq[4][2];
            #pragma unroll
            for (int it = 0; it < 4; ++it) {
                pq[it][0] = pk2(p[it][0] * inv, p[it][1] * inv);
                pq[it][1] = pk2(p[it][2] * inv, p[it][3] * inv);
            }
            // PV: out^T(:, this q-tile) += V^T · P^T
            #pragma unroll
            for (int kh = 0; kh < 2; ++kh) {
                bf16x8 pf = mkfrag(sel2(pq[2 * kh][0], pq[2 * kh + 1][0], srcA, ghi),
                                   sel2(pq[2 * kh][1], pq[2 * kh + 1][1], srcA, ghi),
                                   sel2(pq[2 * kh][0], pq[2 * kh + 1][0], srcB, ghi),
                                   sel2(pq[2 * kh][1], pq[2 * kh + 1][1], srcB, ghi));
                #pragma unroll
                for (int dt = 0; dt < 2; ++dt)
                    oacc[dt][jt] = __builtin_amdgcn_mfma_f32_16x16x32_bf16(vf[kh][dt], pf, oacc[dt][jt], 0, 0, 0);
            }
        }

        // ---------- attn_out -> aob as [64 t][256 d] bf16, 512B rows ----------
        #pragma unroll
        for (int dt = 0; dt < 2; ++dt) {
            #pragma unroll
            for (int jt = 0; jt < 4; ++jt) {
                int q = jt * 16 + c;
                int d0 = h * 32 + dt * 16 + 4 * g;
                f32x4 v = oacc[dt][jt];
                *(uint2*)(aob + q * 512 + ((2 * d0) ^ ((q & 7) << 4))) =
                    make_uint2(pk2(v[0], v[1]), pk2(v[2], v[3]));
            }
        }
        __syncthreads();

        // ---------- prefetch next window's x (issue-early), then proj GEMM ----------
        float4 px[8];
        const bool pf_on = (w + 1 < WPB);
        if (pf_on) {
            const float* xw2 = x + (size_t)(b + 1) * (NTOK * DIMC);
            #pragma unroll
            for (int it = 0; it < 8; ++it) {
                int idx = it * 512 + tid;
                int t = idx >> 6;
                int d0 = (idx & 63) * 4;
                px[it] = make_float4(0.f, 0.f, 0.f, 0.f);
                if (t < NTOK) px[it] = *(const float4*)(xw2 + t * DIMC + d0);
            }
        }
        {
            f32x4 pacc[2][4];
            #pragma unroll
            for (int j = 0; j < 2; ++j)
                #pragma unroll
                for (int mt = 0; mt < 4; ++mt) pacc[j][mt] = fzero;
            #pragma unroll
            for (int ks = 0; ks < 8; ++ks) {
                int kk = ks * 32;
                bf16x8 af[4];
                #pragma unroll
                for (int mt = 0; mt < 4; ++mt) { int t = mt * 16 + c; af[mt] = XFR(aob, t, kk); }
                #pragma unroll
                for (int j = 0; j < 2; ++j) {
                    int o = (wid * 2 + j) * 16 + c;
                    bf16x8 bfr = *(const bf16x8*)(wproj + (size_t)o * 256 + kk + 8 * g);
                    #pragma unroll
                    for (int mt = 0; mt < 4; ++mt)
                        pacc[j][mt] = __builtin_amdgcn_mfma_f32_16x16x32_bf16(af[mt], bfr, pacc[j][mt], 0, 0, 0);
                }
            }
            float* ob = out + (size_t)b * (NTOK * DIMC);
            #pragma unroll
            for (int j = 0; j < 2; ++j) {
                int o = (wid * 2 + j) * 16 + c;
                float bias = bproj[o];
                #pragma unroll
                for (int mt = 0; mt < 4; ++mt) {
                    #pragma unroll
                    for (int r = 0; r < 4; ++r) {
                        int t = mt * 16 + g * 4 + r;
                        if (t < NTOK) ob[t * DIMC + o] = pacc[j][mt][r] + bias;
                    }
                }
            }
        }
        // ---------- write prefetched x into the other buffer ----------
        if (pf_on) {
            #pragma unroll
            for (int it = 0; it < 8; ++it) {
                int idx = it * 512 + tid;
                int t = idx >> 6;
                int d0 = (idx & 63) * 4;
                *(uint2*)(xn + t * 512 + ((d0 * 2) ^ ((t & 7) << 4))) =
                    make_uint2(pk2(px[it].x, px[it].y), pk2(px[it].z, px[it].w));
            }
        }
        __syncthreads();
        #undef XFR
    }
}

extern "C" void kernel_launch(void* const* d_in, const int* in_sizes, int n_in,
                              void* d_out, int out_size, void* d_ws, size_t ws_size,
                              hipStream_t stream) {
    const float* x    = (const float*)d_in[0];
    const float* mask = (const float*)d_in[1];
    const float* wq   = (const float*)d_in[2];
    const float* bq   = (const float*)d_in[3];
    const float* wp   = (const float*)d_in[4];
    const float* bp   = (const float*)d_in[5];
    float* o = (float*)d_out;

    unsigned short* wqb = (unsigned short*)d_ws;          // 768*256 bf16
    unsigned short* wpb = wqb + 768 * 256;                // 256*256 bf16

    convert_weights<<<768, 256, 0, stream>>>(wq, wp, wqb, wpb);
    win_attn_fused<<<8192 / WPB, 512, 0, stream>>>(x, mask, wqb, bq, wpb, bp, o);
}

// Round 6
// 736.334 us; speedup vs baseline: 2.0319x; 2.0319x over previous
//
#include <hip/hip_runtime.h>
#include <hip/hip_bf16.h>

#define NTOK 49
#define DIMC 256

typedef __attribute__((ext_vector_type(8))) short bf16x8;
typedef __attribute__((ext_vector_type(4))) float f32x4;

static __device__ __forceinline__ unsigned pk2(float a, float b) {
    union { __hip_bfloat16 h; unsigned short u; } ua, ub;
    ua.h = __float2bfloat16(a);
    ub.h = __float2bfloat16(b);
    return (unsigned)ua.u | ((unsigned)ub.u << 16);
}

static __device__ __forceinline__ bf16x8 mkfrag(unsigned w0, unsigned w1, unsigned w2, unsigned w3) {
    union { bf16x8 v; unsigned u[4]; } t;
    t.u[0] = w0; t.u[1] = w1; t.u[2] = w2; t.u[3] = w3;
    return t.v;
}

// pull both candidate halves from src lane, select by target's g>>1
static __device__ __forceinline__ unsigned sel2(unsigned lo, unsigned hi, int src, int ghi) {
    unsigned a = __shfl(lo, src);
    unsigned b = __shfl(hi, src);
    return ghi ? b : a;
}

__global__ void convert_weights(const float* __restrict__ wq, const float* __restrict__ wp,
                                unsigned short* __restrict__ wqb, unsigned short* __restrict__ wpb) {
    int i = blockIdx.x * 256 + threadIdx.x;
    if (i < 768 * 256) {
        union { __hip_bfloat16 h; unsigned short u; } t;
        t.h = __float2bfloat16(wq[i]);
        wqb[i] = t.u;
    }
    if (i < 256 * 256) {
        union { __hip_bfloat16 h; unsigned short u; } t;
        t.h = __float2bfloat16(wp[i]);
        wpb[i] = t.u;
    }
}

// One window per block, 16 waves = 1024 threads. Wave (h=wid>>1, qh=wid&1):
//   phase A: computes K^T (qh=0) or Q^T (qh=1) of head h, plus V columns d in [qh*16,qh*16+16),
//            sharing one set of x fragments for both GEMMs; results exchanged via LDS.
//   attn   : wave handles query-half qh of head h (ka/qf/vf read straight from LDS, no shuffles).
//   proj   : wave owns one 16-col n-tile.
// 16-wave block forces combined (VGPR+AGPR) <= 128/wave -> 4 waves/SIMD co-resident.
// LDS (128KB):
//   xb  [0,32K)    : x bf16 [64 t][512B rows] XOR ((t&7)<<4); reused as attn_out [64 t][256 d] after attn
//   kqv [32K,128K) : per head 12KB: K[64 t][64B] XOR ((t&3)<<4) | Q same | V^T[32 d][128B] XOR ((d&7)<<4)
// Mask is read directly from global (L2-served).
__launch_bounds__(1024, 1)
__global__ void win_attn_fused(const float* __restrict__ x, const float* __restrict__ mask,
                               const unsigned short* __restrict__ wqkv, const float* __restrict__ bqkv,
                               const unsigned short* __restrict__ wproj, const float* __restrict__ bproj,
                               float* __restrict__ out) {
    __shared__ __align__(16) char lds[131072];
    char* const xb  = lds;
    char* const kqv = lds + 32768;

    const int b = blockIdx.x;
    const int tid = threadIdx.x;
    const int lane = tid & 63;
    const int wid = tid >> 6;     // 0..15
    const int c = lane & 15;
    const int g = lane >> 4;
    const int h = wid >> 1;
    const int qh = wid & 1;
    const int srcA = c + 16 * ((2 * g) & 3);
    const int srcB = c + 16 * ((2 * g + 1) & 3);
    const int ghi = g >> 1;
    const float scale = 0.17677669529663687f;  // 32^-0.5
    const f32x4 fzero = {0.f, 0.f, 0.f, 0.f};

    // ---------- stage x (bf16) ----------
    {
        const float* xw = x + (size_t)b * (NTOK * DIMC);
        #pragma unroll
        for (int it = 0; it < 4; ++it) {
            int idx = it * 1024 + tid;
            int t = idx >> 6;
            int d0 = (idx & 63) * 4;
            float4 v = make_float4(0.f, 0.f, 0.f, 0.f);
            if (t < NTOK) v = *(const float4*)(xw + t * DIMC + d0);
            *(uint2*)(xb + t * 512 + ((d0 * 2) ^ ((t & 7) << 4))) =
                make_uint2(pk2(v.x, v.y), pk2(v.z, v.w));
        }
    }
    __syncthreads();

    #define XFR(base_, t_, kk_) \
        (*(const bf16x8*)((base_) + (t_) * 512 + ((2 * ((kk_) + 8 * g)) ^ (((t_) & 7) << 4))))

    char* const Kh = kqv + h * 12288;
    char* const Qh = Kh + 4096;
    char* const Vh = Kh + 8192;

    // ---------- phase A: K^T or Q^T (full head) + V half, shared x frags ----------
    {
        f32x4 aKQ[2][4], aV[4];
        #pragma unroll
        for (int md = 0; md < 2; ++md)
            #pragma unroll
            for (int j2 = 0; j2 < 4; ++j2) aKQ[md][j2] = fzero;
        #pragma unroll
        for (int mt = 0; mt < 4; ++mt) aV[mt] = fzero;

        const int woff = qh ? (h * 32) : (256 + h * 32);
        #pragma unroll
        for (int ks = 0; ks < 8; ++ks) {
            int kk = ks * 32;
            bf16x8 xf[4];
            #pragma unroll
            for (int tt = 0; tt < 4; ++tt) { int t = tt * 16 + c; xf[tt] = XFR(xb, t, kk); }
            #pragma unroll
            for (int md = 0; md < 2; ++md) {
                bf16x8 wkq = *(const bf16x8*)(wqkv + (size_t)(woff + md * 16 + c) * 256 + kk + 8 * g);
                #pragma unroll
                for (int j2 = 0; j2 < 4; ++j2)
                    aKQ[md][j2] = __builtin_amdgcn_mfma_f32_16x16x32_bf16(wkq, xf[j2], aKQ[md][j2], 0, 0, 0);
            }
            bf16x8 wv = *(const bf16x8*)(wqkv + (size_t)(512 + h * 32 + qh * 16 + c) * 256 + kk + 8 * g);
            #pragma unroll
            for (int mt = 0; mt < 4; ++mt)
                aV[mt] = __builtin_amdgcn_mfma_f32_16x16x32_bf16(xf[mt], wv, aV[mt], 0, 0, 0);
        }

        // write K (qh=0) or Q (qh=1): rows t (64B, XOR (t&3)<<4), 4 consecutive d packed per store
        char* kqdst = Kh + qh * 4096;
        const float* bb = bqkv + (qh ? 0 : 256) + h * 32;
        #pragma unroll
        for (int md = 0; md < 2; ++md) {
            const float* b4 = bb + md * 16 + 4 * g;
            float b0 = b4[0], b1 = b4[1], b2 = b4[2], b3 = b4[3];
            #pragma unroll
            for (int j2 = 0; j2 < 4; ++j2) {
                int t = j2 * 16 + c;
                int d0 = md * 16 + 4 * g;
                f32x4 v = aKQ[md][j2];
                float v0 = v[0] + b0, v1 = v[1] + b1, v2 = v[2] + b2, v3 = v[3] + b3;
                if (qh) { v0 *= scale; v1 *= scale; v2 *= scale; v3 *= scale; }
                *(uint2*)(kqdst + t * 64 + ((d0 * 2) ^ ((t & 3) << 4))) =
                    make_uint2(pk2(v0, v1), pk2(v2, v3));
            }
        }
        // write V^T: rows d (128B, XOR (d&7)<<4), 4 consecutive t packed per store
        float bv = bqkv[512 + h * 32 + qh * 16 + c];
        #pragma unroll
        for (int mt = 0; mt < 4; ++mt) {
            int t0 = mt * 16 + 4 * g;
            int d = qh * 16 + c;
            f32x4 v = aV[mt];
            *(uint2*)(Vh + d * 128 + ((t0 * 2) ^ ((d & 7) << 4))) =
                make_uint2(pk2(v[0] + bv, v[1] + bv), pk2(v[2] + bv, v[3] + bv));
        }
    }
    __syncthreads();

    // ---------- attention: wave = (head h, query-half qh) ----------
    f32x4 oacc[2][2];
    {
        bf16x8 ka[4], qf[2], vf[2][2];
        #pragma unroll
        for (int it = 0; it < 4; ++it) {
            int key = it * 16 + c;
            ka[it] = *(const bf16x8*)(Kh + key * 64 + ((g * 16) ^ ((key & 3) << 4)));
        }
        #pragma unroll
        for (int jl = 0; jl < 2; ++jl) {
            int q = (qh * 2 + jl) * 16 + c;
            qf[jl] = *(const bf16x8*)(Qh + q * 64 + ((g * 16) ^ ((q & 3) << 4)));
        }
        #pragma unroll
        for (int kh = 0; kh < 2; ++kh)
            #pragma unroll
            for (int dt = 0; dt < 2; ++dt) {
                int d = dt * 16 + c;
                vf[kh][dt] = *(const bf16x8*)(Vh + d * 128 +
                                              (((kh * 32 + g * 8) * 2) ^ ((d & 7) << 4)));
            }
        #pragma unroll
        for (int dt = 0; dt < 2; ++dt)
            #pragma unroll
            for (int jl = 0; jl < 2; ++jl) oacc[dt][jl] = fzero;

        const float* mw = mask + (size_t)b * (NTOK * NTOK);
        #pragma unroll
        for (int jl = 0; jl < 2; ++jl) {
            int jt = qh * 2 + jl;
            int q = jt * 16 + c;
            int qc = (q < NTOK) ? q : (NTOK - 1);   // clamp: q>=49 rows discarded at store
            const float* mrow = mw + qc * NTOK;
            f32x4 mv0 = *(const f32x4*)(mrow + 0 + g * 4);
            f32x4 mv1 = *(const f32x4*)(mrow + 16 + g * 4);
            f32x4 mv2 = *(const f32x4*)(mrow + 32 + g * 4);
            float m48 = mrow[48];                    // only key=48 valid in tile 3
            float p[4][4];
            {
                f32x4 s = __builtin_amdgcn_mfma_f32_16x16x32_bf16(ka[0], qf[jl], fzero, 0, 0, 0);
                #pragma unroll
                for (int r = 0; r < 4; ++r) p[0][r] = s[r] + mv0[r];
            }
            {
                f32x4 s = __builtin_amdgcn_mfma_f32_16x16x32_bf16(ka[1], qf[jl], fzero, 0, 0, 0);
                #pragma unroll
                for (int r = 0; r < 4; ++r) p[1][r] = s[r] + mv1[r];
            }
            {
                f32x4 s = __builtin_amdgcn_mfma_f32_16x16x32_bf16(ka[2], qf[jl], fzero, 0, 0, 0);
                #pragma unroll
                for (int r = 0; r < 4; ++r) p[2][r] = s[r] + mv2[r];
            }
            {
                f32x4 s = __builtin_amdgcn_mfma_f32_16x16x32_bf16(ka[3], qf[jl], fzero, 0, 0, 0);
                #pragma unroll
                for (int r = 0; r < 4; ++r)
                    p[3][r] = (g == 0 && r == 0) ? (s[0] + m48) : -1e30f;
            }
            // softmax over keys; lanes {c, c+16, c+32, c+48} share a query column
            float m = -1e30f;
            #pragma unroll
            for (int it = 0; it < 4; ++it)
                #pragma unroll
                for (int r = 0; r < 4; ++r) m = fmaxf(m, p[it][r]);
            m = fmaxf(m, __shfl_xor(m, 16));
            m = fmaxf(m, __shfl_xor(m, 32));
            float ssum = 0.f;
            #pragma unroll
            for (int it = 0; it < 4; ++it)
                #pragma unroll
                for (int r = 0; r < 4; ++r) {
                    float e = __expf(p[it][r] - m);
                    p[it][r] = e;
                    ssum += e;
                }
            ssum += __shfl_xor(ssum, 16);
            ssum += __shfl_xor(ssum, 32);
            float inv = 1.0f / ssum;
            unsigned pq[4][2];
            #pragma unroll
            for (int it = 0; it < 4; ++it) {
                pq[it][0] = pk2(p[it][0] * inv, p[it][1] * inv);
                pq[it][1] = pk2(p[it][2] * inv, p[it][3] * inv);
            }
            // PV: out^T(:, this q-tile) += V^T · P^T
            #pragma unroll
            for (int kh = 0; kh < 2; ++kh) {
                bf16x8 pf = mkfrag(sel2(pq[2 * kh][0], pq[2 * kh + 1][0], srcA, ghi),
                                   sel2(pq[2 * kh][1], pq[2 * kh + 1][1], srcA, ghi),
                                   sel2(pq[2 * kh][0], pq[2 * kh + 1][0], srcB, ghi),
                                   sel2(pq[2 * kh][1], pq[2 * kh + 1][1], srcB, ghi));
                #pragma unroll
                for (int dt = 0; dt < 2; ++dt)
                    oacc[dt][jl] = __builtin_amdgcn_mfma_f32_16x16x32_bf16(vf[kh][dt], pf, oacc[dt][jl], 0, 0, 0);
            }
        }
    }

    // attn_out -> xb region (x dead since the post-phase-A barrier) as [64 t][256 d]
    #pragma unroll
    for (int dt = 0; dt < 2; ++dt) {
        #pragma unroll
        for (int jl = 0; jl < 2; ++jl) {
            int q = (qh * 2 + jl) * 16 + c;
            int d0 = h * 32 + dt * 16 + 4 * g;
            f32x4 v = oacc[dt][jl];
            *(uint2*)(xb + q * 512 + ((2 * d0) ^ ((q & 7) << 4))) =
                make_uint2(pk2(v[0], v[1]), pk2(v[2], v[3]));
        }
    }
    __syncthreads();

    // ---------- proj GEMM: 16 waves x one 16-col n-tile ----------
    {
        f32x4 pacc[4];
        #pragma unroll
        for (int mt = 0; mt < 4; ++mt) pacc[mt] = fzero;
        const int o = wid * 16 + c;
        #pragma unroll
        for (int ks = 0; ks < 8; ++ks) {
            int kk = ks * 32;
            bf16x8 bfr = *(const bf16x8*)(wproj + (size_t)o * 256 + kk + 8 * g);
            #pragma unroll
            for (int mt = 0; mt < 4; ++mt) {
                int t = mt * 16 + c;
                bf16x8 af = XFR(xb, t, kk);
                pacc[mt] = __builtin_amdgcn_mfma_f32_16x16x32_bf16(af, bfr, pacc[mt], 0, 0, 0);
            }
        }
        float bias = bproj[o];
        float* ob = out + (size_t)b * (NTOK * DIMC);
        #pragma unroll
        for (int mt = 0; mt < 4; ++mt) {
            #pragma unroll
            for (int r = 0; r < 4; ++r) {
                int t = mt * 16 + g * 4 + r;
                if (t < NTOK) ob[t * DIMC + o] = pacc[mt][r] + bias;
            }
        }
    }
    #undef XFR
}

extern "C" void kernel_launch(void* const* d_in, const int* in_sizes, int n_in,
                              void* d_out, int out_size, void* d_ws, size_t ws_size,
                              hipStream_t stream) {
    const float* x    = (const float*)d_in[0];
    const float* mask = (const float*)d_in[1];
    const float* wq   = (const float*)d_in[2];
    const float* bq   = (const float*)d_in[3];
    const float* wp   = (const float*)d_in[4];
    const float* bp   = (const float*)d_in[5];
    float* o = (float*)d_out;

    unsigned short* wqb = (unsigned short*)d_ws;          // 768*256 bf16
    unsigned short* wpb = wqb + 768 * 256;                // 256*256 bf16

    convert_weights<<<768, 256, 0, stream>>>(wq, wp, wqb, wpb);
    win_attn_fused<<<8192, 1024, 0, stream>>>(x, mask, wqb, bq, wpb, bp, o);
}

// Round 7
// 718.056 us; speedup vs baseline: 2.0836x; 1.0255x over previous
//
#include <hip/hip_runtime.h>
#include <hip/hip_bf16.h>

#define NTOK 49
#define DIMC 256

typedef __attribute__((ext_vector_type(8))) short bf16x8;
typedef __attribute__((ext_vector_type(4))) float f32x4;

static __device__ __forceinline__ unsigned pk2(float a, float b) {
    union { __hip_bfloat16 h; unsigned short u; } ua, ub;
    ua.h = __float2bfloat16(a);
    ub.h = __float2bfloat16(b);
    return (unsigned)ua.u | ((unsigned)ub.u << 16);
}

static __device__ __forceinline__ bf16x8 mkfrag(unsigned w0, unsigned w1, unsigned w2, unsigned w3) {
    union { bf16x8 v; unsigned u[4]; } t;
    t.u[0] = w0; t.u[1] = w1; t.u[2] = w2; t.u[3] = w3;
    return t.v;
}

// pull both candidate halves from src lane, select by target's g>>1
static __device__ __forceinline__ unsigned sel2(unsigned lo, unsigned hi, int src, int ghi) {
    unsigned a = __shfl(lo, src);
    unsigned b = __shfl(hi, src);
    return ghi ? b : a;
}

__global__ void convert_weights(const float* __restrict__ wq, const float* __restrict__ wp,
                                unsigned short* __restrict__ wqb, unsigned short* __restrict__ wpb) {
    int i = blockIdx.x * 256 + threadIdx.x;
    if (i < 768 * 256) {
        union { __hip_bfloat16 h; unsigned short u; } t;
        t.h = __float2bfloat16(wq[i]);
        wqb[i] = t.u;
    }
    if (i < 256 * 256) {
        union { __hip_bfloat16 h; unsigned short u; } t;
        t.h = __float2bfloat16(wp[i]);
        wpb[i] = t.u;
    }
}

// One window per block, 16 waves = 1024 threads. Wave (h=wid>>1, qh=wid&1):
//   phase A: computes K^T (qh=0) or Q^T (qh=1) of head h, plus V columns d in [qh*16,qh*16+16),
//            sharing one set of x fragments for both GEMMs; results exchanged via LDS.
//   attn   : wave handles query-half qh of head h (ka/qf/vf read straight from LDS, no shuffles).
//   proj   : wave owns one 16-col n-tile.
// LDS caps CU at 16 waves (1 block) -> amdgpu_waves_per_eu(4,4) unlocks the 128-VGPR tier
// (round-6 compiled at 60 VGPR targeting a phantom 8-waves/EU tier -> ILP-starved).
// LDS (128KB):
//   xb  [0,32K)    : x bf16 [64 t][512B rows] XOR ((t&7)<<4); reused as attn_out [64 t][256 d] after attn
//   kqv [32K,128K) : per head 12KB: K[64 t][64B] XOR ((t&3)<<4) | Q same | V^T[32 d][128B] XOR ((d&7)<<4)
// Mask is read directly from global (L2/L3-served), hoisted to phase start.
__launch_bounds__(1024, 4)
__attribute__((amdgpu_waves_per_eu(4, 4)))
__global__ void win_attn_fused(const float* __restrict__ x, const float* __restrict__ mask,
                               const unsigned short* __restrict__ wqkv, const float* __restrict__ bqkv,
                               const unsigned short* __restrict__ wproj, const float* __restrict__ bproj,
                               float* __restrict__ out) {
    __shared__ __align__(16) char lds[131072];
    char* const xb  = lds;
    char* const kqv = lds + 32768;

    const int b = blockIdx.x;
    const int tid = threadIdx.x;
    const int lane = tid & 63;
    const int wid = tid >> 6;     // 0..15
    const int c = lane & 15;
    const int g = lane >> 4;
    const int h = wid >> 1;
    const int qh = wid & 1;
    const int srcA = c + 16 * ((2 * g) & 3);
    const int srcB = c + 16 * ((2 * g + 1) & 3);
    const int ghi = g >> 1;
    const float scale = 0.17677669529663687f;  // 32^-0.5
    const f32x4 fzero = {0.f, 0.f, 0.f, 0.f};

    // ---------- stage x (bf16) ----------
    {
        const float* xw = x + (size_t)b * (NTOK * DIMC);
        #pragma unroll
        for (int it = 0; it < 4; ++it) {
            int idx = it * 1024 + tid;
            int t = idx >> 6;
            int d0 = (idx & 63) * 4;
            float4 v = make_float4(0.f, 0.f, 0.f, 0.f);
            if (t < NTOK) v = *(const float4*)(xw + t * DIMC + d0);
            *(uint2*)(xb + t * 512 + ((d0 * 2) ^ ((t & 7) << 4))) =
                make_uint2(pk2(v.x, v.y), pk2(v.z, v.w));
        }
    }
    __syncthreads();

    #define XFR(base_, t_, kk_) \
        (*(const bf16x8*)((base_) + (t_) * 512 + ((2 * ((kk_) + 8 * g)) ^ (((t_) & 7) << 4))))

    char* const Kh = kqv + h * 12288;
    char* const Qh = Kh + 4096;
    char* const Vh = Kh + 8192;

    // ---------- phase A: K^T or Q^T (full head) + V half, shared x frags ----------
    {
        f32x4 aKQ[2][4], aV[4];
        #pragma unroll
        for (int md = 0; md < 2; ++md)
            #pragma unroll
            for (int j2 = 0; j2 < 4; ++j2) aKQ[md][j2] = fzero;
        #pragma unroll
        for (int mt = 0; mt < 4; ++mt) aV[mt] = fzero;

        const int woff = qh ? (h * 32) : (256 + h * 32);
        const unsigned short* wkq_base = wqkv + (size_t)(woff + c) * 256 + 8 * g;
        const unsigned short* wv_base  = wqkv + (size_t)(512 + h * 32 + qh * 16 + c) * 256 + 8 * g;
        #pragma unroll
        for (int ks = 0; ks < 8; ++ks) {
            int kk = ks * 32;
            bf16x8 xf[4];
            #pragma unroll
            for (int tt = 0; tt < 4; ++tt) { int t = tt * 16 + c; xf[tt] = XFR(xb, t, kk); }
            bf16x8 wkq0 = *(const bf16x8*)(wkq_base + kk);
            bf16x8 wkq1 = *(const bf16x8*)(wkq_base + 16 * 256 + kk);
            bf16x8 wv   = *(const bf16x8*)(wv_base + kk);
            #pragma unroll
            for (int j2 = 0; j2 < 4; ++j2) {
                aKQ[0][j2] = __builtin_amdgcn_mfma_f32_16x16x32_bf16(wkq0, xf[j2], aKQ[0][j2], 0, 0, 0);
                aKQ[1][j2] = __builtin_amdgcn_mfma_f32_16x16x32_bf16(wkq1, xf[j2], aKQ[1][j2], 0, 0, 0);
                aV[j2]     = __builtin_amdgcn_mfma_f32_16x16x32_bf16(xf[j2], wv, aV[j2], 0, 0, 0);
            }
        }

        // write K (qh=0) or Q (qh=1): rows t (64B, XOR (t&3)<<4), 4 consecutive d packed per store
        char* kqdst = Kh + qh * 4096;
        const float* bb = bqkv + (qh ? 0 : 256) + h * 32;
        #pragma unroll
        for (int md = 0; md < 2; ++md) {
            const float* b4 = bb + md * 16 + 4 * g;
            float b0 = b4[0], b1 = b4[1], b2 = b4[2], b3 = b4[3];
            #pragma unroll
            for (int j2 = 0; j2 < 4; ++j2) {
                int t = j2 * 16 + c;
                int d0 = md * 16 + 4 * g;
                f32x4 v = aKQ[md][j2];
                float v0 = v[0] + b0, v1 = v[1] + b1, v2 = v[2] + b2, v3 = v[3] + b3;
                if (qh) { v0 *= scale; v1 *= scale; v2 *= scale; v3 *= scale; }
                *(uint2*)(kqdst + t * 64 + ((d0 * 2) ^ ((t & 3) << 4))) =
                    make_uint2(pk2(v0, v1), pk2(v2, v3));
            }
        }
        // write V^T: rows d (128B, XOR (d&7)<<4), 4 consecutive t packed per store
        float bv = bqkv[512 + h * 32 + qh * 16 + c];
        #pragma unroll
        for (int mt = 0; mt < 4; ++mt) {
            int t0 = mt * 16 + 4 * g;
            int d = qh * 16 + c;
            f32x4 v = aV[mt];
            *(uint2*)(Vh + d * 128 + ((t0 * 2) ^ ((d & 7) << 4))) =
                make_uint2(pk2(v[0] + bv, v[1] + bv), pk2(v[2] + bv, v[3] + bv));
        }
    }
    __syncthreads();

    // ---------- attention: wave = (head h, query-half qh) ----------
    f32x4 oacc[2][2];
    {
        // mask loads hoisted: L2/L3 latency overlaps the LDS fragment reads + QK^T MFMAs
        const float* mw = mask + (size_t)b * (NTOK * NTOK);
        f32x4 mv[2][3];
        float m48[2];
        #pragma unroll
        for (int jl = 0; jl < 2; ++jl) {
            int q = (qh * 2 + jl) * 16 + c;
            int qc = (q < NTOK) ? q : (NTOK - 1);   // clamp: q>=49 rows discarded at store
            const float* mrow = mw + qc * NTOK;
            mv[jl][0] = *(const f32x4*)(mrow + 0 + g * 4);
            mv[jl][1] = *(const f32x4*)(mrow + 16 + g * 4);
            mv[jl][2] = *(const f32x4*)(mrow + 32 + g * 4);
            m48[jl] = mrow[48];                      // only key=48 valid in tile 3
        }

        bf16x8 ka[4], qf[2], vf[2][2];
        #pragma unroll
        for (int it = 0; it < 4; ++it) {
            int key = it * 16 + c;
            ka[it] = *(const bf16x8*)(Kh + key * 64 + ((g * 16) ^ ((key & 3) << 4)));
        }
        #pragma unroll
        for (int jl = 0; jl < 2; ++jl) {
            int q = (qh * 2 + jl) * 16 + c;
            qf[jl] = *(const bf16x8*)(Qh + q * 64 + ((g * 16) ^ ((q & 3) << 4)));
        }
        #pragma unroll
        for (int kh = 0; kh < 2; ++kh)
            #pragma unroll
            for (int dt = 0; dt < 2; ++dt) {
                int d = dt * 16 + c;
                vf[kh][dt] = *(const bf16x8*)(Vh + d * 128 +
                                              (((kh * 32 + g * 8) * 2) ^ ((d & 7) << 4)));
            }
        #pragma unroll
        for (int dt = 0; dt < 2; ++dt)
            #pragma unroll
            for (int jl = 0; jl < 2; ++jl) oacc[dt][jl] = fzero;

        #pragma unroll
        for (int jl = 0; jl < 2; ++jl) {
            float p[4][4];
            {
                f32x4 s = __builtin_amdgcn_mfma_f32_16x16x32_bf16(ka[0], qf[jl], fzero, 0, 0, 0);
                #pragma unroll
                for (int r = 0; r < 4; ++r) p[0][r] = s[r] + mv[jl][0][r];
            }
            {
                f32x4 s = __builtin_amdgcn_mfma_f32_16x16x32_bf16(ka[1], qf[jl], fzero, 0, 0, 0);
                #pragma unroll
                for (int r = 0; r < 4; ++r) p[1][r] = s[r] + mv[jl][1][r];
            }
            {
                f32x4 s = __builtin_amdgcn_mfma_f32_16x16x32_bf16(ka[2], qf[jl], fzero, 0, 0, 0);
                #pragma unroll
                for (int r = 0; r < 4; ++r) p[2][r] = s[r] + mv[jl][2][r];
            }
            {
                f32x4 s = __builtin_amdgcn_mfma_f32_16x16x32_bf16(ka[3], qf[jl], fzero, 0, 0, 0);
                #pragma unroll
                for (int r = 0; r < 4; ++r)
                    p[3][r] = (g == 0 && r == 0) ? (s[0] + m48[jl]) : -1e30f;
            }
            // softmax over keys; lanes {c, c+16, c+32, c+48} share a query column
            float m = -1e30f;
            #pragma unroll
            for (int it = 0; it < 4; ++it)
                #pragma unroll
                for (int r = 0; r < 4; ++r) m = fmaxf(m, p[it][r]);
            m = fmaxf(m, __shfl_xor(m, 16));
            m = fmaxf(m, __shfl_xor(m, 32));
            float ssum = 0.f;
            #pragma unroll
            for (int it = 0; it < 4; ++it)
                #pragma unroll
                for (int r = 0; r < 4; ++r) {
                    float e = __expf(p[it][r] - m);
                    p[it][r] = e;
                    ssum += e;
                }
            ssum += __shfl_xor(ssum, 16);
            ssum += __shfl_xor(ssum, 32);
            float inv = 1.0f / ssum;
            unsigned pq[4][2];
            #pragma unroll
            for (int it = 0; it < 4; ++it) {
                pq[it][0] = pk2(p[it][0] * inv, p[it][1] * inv);
                pq[it][1] = pk2(p[it][2] * inv, p[it][3] * inv);
            }
            // PV: out^T(:, this q-tile) += V^T · P^T
            #pragma unroll
            for (int kh = 0; kh < 2; ++kh) {
                bf16x8 pf = mkfrag(sel2(pq[2 * kh][0], pq[2 * kh + 1][0], srcA, ghi),
                                   sel2(pq[2 * kh][1], pq[2 * kh + 1][1], srcA, ghi),
                                   sel2(pq[2 * kh][0], pq[2 * kh + 1][0], srcB, ghi),
                                   sel2(pq[2 * kh][1], pq[2 * kh + 1][1], srcB, ghi));
                #pragma unroll
                for (int dt = 0; dt < 2; ++dt)
                    oacc[dt][jl] = __builtin_amdgcn_mfma_f32_16x16x32_bf16(vf[kh][dt], pf, oacc[dt][jl], 0, 0, 0);
            }
        }
    }

    // attn_out -> xb region (x dead since the post-phase-A barrier) as [64 t][256 d]
    #pragma unroll
    for (int dt = 0; dt < 2; ++dt) {
        #pragma unroll
        for (int jl = 0; jl < 2; ++jl) {
            int q = (qh * 2 + jl) * 16 + c;
            int d0 = h * 32 + dt * 16 + 4 * g;
            f32x4 v = oacc[dt][jl];
            *(uint2*)(xb + q * 512 + ((2 * d0) ^ ((q & 7) << 4))) =
                make_uint2(pk2(v[0], v[1]), pk2(v[2], v[3]));
        }
    }
    __syncthreads();

    // ---------- proj GEMM: 16 waves x one 16-col n-tile ----------
    {
        f32x4 pacc[4];
        #pragma unroll
        for (int mt = 0; mt < 4; ++mt) pacc[mt] = fzero;
        const int o = wid * 16 + c;
        const unsigned short* wp_base = wproj + (size_t)o * 256 + 8 * g;
        const float bias = bproj[o];
        #pragma unroll
        for (int ks = 0; ks < 8; ++ks) {
            int kk = ks * 32;
            bf16x8 bfr = *(const bf16x8*)(wp_base + kk);
            #pragma unroll
            for (int mt = 0; mt < 4; ++mt) {
                int t = mt * 16 + c;
                bf16x8 af = XFR(xb, t, kk);
                pacc[mt] = __builtin_amdgcn_mfma_f32_16x16x32_bf16(af, bfr, pacc[mt], 0, 0, 0);
            }
        }
        float* ob = out + (size_t)b * (NTOK * DIMC);
        #pragma unroll
        for (int mt = 0; mt < 4; ++mt) {
            #pragma unroll
            for (int r = 0; r < 4; ++r) {
                int t = mt * 16 + g * 4 + r;
                if (t < NTOK) ob[t * DIMC + o] = pacc[mt][r] + bias;
            }
        }
    }
    #undef XFR
}

extern "C" void kernel_launch(void* const* d_in, const int* in_sizes, int n_in,
                              void* d_out, int out_size, void* d_ws, size_t ws_size,
                              hipStream_t stream) {
    const float* x    = (const float*)d_in[0];
    const float* mask = (const float*)d_in[1];
    const float* wq   = (const float*)d_in[2];
    const float* bq   = (const float*)d_in[3];
    const float* wp   = (const float*)d_in[4];
    const float* bp   = (const float*)d_in[5];
    float* o = (float*)d_out;

    unsigned short* wqb = (unsigned short*)d_ws;          // 768*256 bf16
    unsigned short* wpb = wqb + 768 * 256;                // 256*256 bf16

    convert_weights<<<768, 256, 0, stream>>>(wq, wp, wqb, wpb);
    win_attn_fused<<<8192, 1024, 0, stream>>>(x, mask, wqb, bq, wpb, bp, o);
}